// Round 1
// baseline (9112.892 us; speedup 1.0000x reference)
//
#include <hip/hip_runtime.h>

typedef float2 cplx;

constexpr int B_   = 2;
constexpr int C_   = 12;
constexpr int NR   = 96;    // image rows
constexpr int NC_  = 96;    // cols
constexpr int NS   = 48;    // slices
constexpr int NP   = 288;   // padded rows
constexpr int NCOL = NC_ * NS;      // 4608 columns per row
constexpr int NVOX = NR * NCOL;     // 442368 voxels per batch
constexpr int TILE = 48;            // columns per K1/K3 block
constexpr int TILES = NCOL / TILE;  // 96
constexpr int LSTR = 49;            // padded nc-stride in K2 plane LDS (bank-conflict fix)
constexpr int NT_FFT = 512;
constexpr float PI2 = 6.28318530717958647692f;

// scalar workspace slots (floats)
#define SC_RTR   0
#define SC_PAP   2
#define SC_RTR1  4
#define SC_ALPHA 6
#define SC_BETA  8
#define SC_ACT   10

__device__ inline cplx cmulc(cplx a, cplx b){ return make_float2(a.x*b.x - a.y*b.y, a.x*b.y + a.y*b.x); }
__device__ inline cplx cmuljc(cplx a, cplx b){ return make_float2(a.x*b.x + a.y*b.y, a.y*b.x - a.x*b.y); } // a*conj(b)
__device__ inline cplx caddc(cplx a, cplx b){ return make_float2(a.x+b.x, a.y+b.y); }
__device__ inline cplx csubc(cplx a, cplx b){ return make_float2(a.x-b.x, a.y-b.y); }

__device__ inline void atomAddF(float* p, float v){
    __hip_atomic_fetch_add(p, v, __ATOMIC_RELAXED, __HIP_MEMORY_SCOPE_AGENT);
}

// ---------------------------------------------------------------------------
// In-place Stockham radix pass over BATCH interleaved FFTs living in LDS.
// Element i of batch t sits at A[i*ES + t*BS]. Current sub-length NCUR,
// stride S, radix R. tw[k] = exp(-2*pi*i*k/96). Twiddle index p*v*(96/NCUR)
// stays < 96 for all our pass sequences (verified per pass).
// Each thread gathers its butterflies to registers, barrier, scatters back.
// ---------------------------------------------------------------------------
template<int R, int NFULL, int NCUR, int S, int BATCH, int ES, int BS, bool INV>
__device__ inline void sk_pass_ip(cplx* A, const cplx* tw, int tid)
{
    constexpr int M   = NCUR / R;
    constexpr int NBF = (NFULL / R) * BATCH;       // butterflies this pass
    constexpr int NIT = (NBF + NT_FFT - 1) / NT_FFT;
    constexpr int TS  = 96 / NCUR;
    cplx v[NIT][4];
    #pragma unroll
    for (int it = 0; it < NIT; ++it) {
        const int w = tid + it * NT_FFT;
        if (w < NBF) {
            const int t = w % BATCH;
            const int j = w / BATCH;
            const int p = j / S;
            const int q = j - p * S;
            const int xb = (q + S * p) * ES + t * BS;
            constexpr int US = S * M * ES;
            if constexpr (R == 2) {
                cplx a0 = A[xb], a1 = A[xb + US];
                cplx w1 = tw[p * TS]; if (INV) w1.y = -w1.y;
                v[it][0] = caddc(a0, a1);
                v[it][1] = cmulc(csubc(a0, a1), w1);
            } else if constexpr (R == 3) {
                cplx a0 = A[xb], a1 = A[xb + US], a2 = A[xb + 2*US];
                cplx w1 = tw[p * TS], w2 = tw[2 * p * TS];
                if (INV) { w1.y = -w1.y; w2.y = -w2.y; }
                cplx t1 = caddc(a1, a2), t2 = csubc(a1, a2);
                cplx m1 = make_float2(a0.x - 0.5f * t1.x, a0.y - 0.5f * t1.y);
                const float s3 = INV ? -0.8660254037844386f : 0.8660254037844386f;
                cplx b1 = make_float2(m1.x + s3 * t2.y, m1.y - s3 * t2.x);
                cplx b2 = make_float2(m1.x - s3 * t2.y, m1.y + s3 * t2.x);
                v[it][0] = caddc(a0, t1);
                v[it][1] = cmulc(b1, w1);
                v[it][2] = cmulc(b2, w2);
            } else { // R == 4
                cplx a0 = A[xb], a1 = A[xb + US], a2 = A[xb + 2*US], a3 = A[xb + 3*US];
                cplx w1 = tw[p * TS], w2 = tw[2 * p * TS], w3 = tw[3 * p * TS];
                if (INV) { w1.y = -w1.y; w2.y = -w2.y; w3.y = -w3.y; }
                cplx t0 = caddc(a0, a2), t1 = csubc(a0, a2);
                cplx t2 = caddc(a1, a3), t3 = csubc(a1, a3);
                cplx it3 = INV ? make_float2(-t3.y, t3.x) : make_float2(t3.y, -t3.x);
                v[it][0] = caddc(t0, t2);
                v[it][1] = cmulc(caddc(t1, it3), w1);
                v[it][2] = cmulc(csubc(t0, t2), w2);
                v[it][3] = cmulc(csubc(t1, it3), w3);
            }
        }
    }
    __syncthreads();
    #pragma unroll
    for (int it = 0; it < NIT; ++it) {
        const int w = tid + it * NT_FFT;
        if (w < NBF) {
            const int t = w % BATCH;
            const int j = w / BATCH;
            const int p = j / S;
            const int q = j - p * S;
            const int yb = (q + S * R * p) * ES + t * BS;
            #pragma unroll
            for (int u = 0; u < R; ++u) A[yb + u * S * ES] = v[it][u];
        }
    }
    __syncthreads();
}

template<int ES, int BS, int BATCH, bool INV>
__device__ inline void fft96_ip(cplx* A, const cplx* tw96, int tid){
    sk_pass_ip<4, 96, 96,  1, BATCH, ES, BS, INV>(A, tw96, tid);
    sk_pass_ip<4, 96, 24,  4, BATCH, ES, BS, INV>(A, tw96, tid);
    sk_pass_ip<2, 96,  6, 16, BATCH, ES, BS, INV>(A, tw96, tid);
    sk_pass_ip<3, 96,  3, 32, BATCH, ES, BS, INV>(A, tw96, tid);
}
template<int ES, int BS, int BATCH, bool INV>
__device__ inline void fft48_ip(cplx* A, const cplx* tw96, int tid){
    sk_pass_ip<4, 48, 48,  1, BATCH, ES, BS, INV>(A, tw96, tid);
    sk_pass_ip<4, 48, 12,  4, BATCH, ES, BS, INV>(A, tw96, tid);
    sk_pass_ip<3, 48,  3, 16, BATCH, ES, BS, INV>(A, tw96, tid);
}

__device__ inline void build_tw96(cplx* tw96, int tid){
    for (int k = tid; k < 96; k += NT_FFT) {
        float s, c; __sincosf(-PI2 * (float)k / 96.f, &s, &c);
        tw96[k] = make_float2(c, s);
    }
}
__device__ inline void build_tw288(cplx* tw288, int tid){
    for (int k = tid; k < 288; k += NT_FFT) {
        float s, c; __sincosf(-PI2 * (float)k / 288.f, &s, &c);
        tw288[k] = make_float2(c, s);
    }
}

// ---------------------------------------------------------------------------
// K1: coil = csm*p; padded row FFT 96->288 (data at rows 96..191):
//     G[3s+a] = e^{-2pi i a/3} * FFT96( x[y] * e^{-2pi i a y/288} )[s]
// One block = one (b, coil, 48-column tile).
// ---------------------------------------------------------------------------
__global__ __launch_bounds__(NT_FFT)
void k_fwd_row(const cplx* __restrict__ pv, const cplx* __restrict__ csm,
               cplx* __restrict__ g, int cg0, int ncg, int ncga)
{
    __shared__ cplx A[NR * TILE];
    __shared__ cplx tw96[96];
    __shared__ cplx tw288[288];
    const int tid = threadIdx.x;
    build_tw96(tw96, tid);
    build_tw288(tw288, tid);

    const int bid  = blockIdx.x;
    const int tile = bid % TILES;
    const int rem  = bid / TILES;
    const int gc   = rem % ncg;
    const int b    = rem / ncg;
    const int c    = cg0 + gc;
    const int colbase = tile * TILE;

    const cplx* pp = pv  + (size_t)b * NVOX;
    const cplx* cs = csm + ((size_t)b * C_ + c) * NVOX;
    cplx* gg = g + (size_t)(b * ncga + gc) * ((size_t)NP * NCOL);

    constexpr int NACC = (NR * TILE) / NT_FFT;   // 9
    cplx xr[NACC];
    #pragma unroll
    for (int i = 0; i < NACC; ++i) {
        const int e = tid + i * NT_FFT;
        const int y = e / TILE, t = e - y * TILE;
        const int gi = y * NCOL + colbase + t;
        xr[i] = cmulc(pp[gi], cs[gi]);
    }

    for (int a = 0; a < 3; ++a) {
        __syncthreads();   // protects A (prev iter readers) + tables on a==0
        #pragma unroll
        for (int i = 0; i < NACC; ++i) {
            const int e = tid + i * NT_FFT;
            const int y = e / TILE;
            cplx x = xr[i];
            if (a) x = cmulc(x, tw288[a * y]);   // a*y <= 190 < 288
            A[e] = x;
        }
        __syncthreads();
        fft96_ip<TILE, 1, TILE, false>(A, tw96, tid);
        const cplx pref = tw96[a * 32];          // e^{-2pi i a/3}
        for (int e = tid; e < NR * TILE; e += NT_FFT) {
            const int s = e / TILE, t = e - s * TILE;
            gg[(size_t)(3 * s + a) * NCOL + colbase + t] = cmulc(A[e], pref);
        }
    }
}

// ---------------------------------------------------------------------------
// K2: per (b, coil, padded row r): plane op
//     g <- conj(w) * IFFT2( mask/4608 * FFT2( w * g ) )
// One block = one 96x48 plane, held in LDS (nc-stride 49 to spread banks).
// ---------------------------------------------------------------------------
__global__ __launch_bounds__(NT_FFT)
void k_plane(cplx* __restrict__ g, const cplx* __restrict__ wpsf,
             const float* __restrict__ mask, int ncg, int ncga)
{
    __shared__ cplx A[NC_ * LSTR];
    __shared__ cplx tw96[96];
    const int tid = threadIdx.x;
    build_tw96(tw96, tid);

    const int bid = blockIdx.x;
    const int r   = bid % NP;
    const int rem = bid / NP;
    const int gc  = rem % ncg;
    const int b   = rem / ncg;

    cplx* gg = g + ((size_t)(b * ncga + gc) * NP + r) * NCOL;
    const cplx*  wp = wpsf + ((size_t)b * NP + r) * NCOL;
    const float* mk = mask + ((size_t)b * NP + r) * NCOL;

    __syncthreads();  // tables
    for (int e = tid; e < NCOL; e += NT_FFT) {
        const int nc = e / NS, ns = e - nc * NS;
        A[nc * LSTR + ns] = cmulc(gg[e], wp[e]);
    }
    __syncthreads();

    fft48_ip<1, LSTR, NC_, false>(A, tw96, tid);   // along ns
    fft96_ip<LSTR, 1, NS, false>(A, tw96, tid);    // along nc

    for (int e = tid; e < NCOL; e += NT_FFT) {
        const int nc = e / NS, ns = e - nc * NS;
        const float m = mk[e] * (1.0f / 4608.0f);  // fold ifft2 norm into mask
        cplx v = A[nc * LSTR + ns];
        v.x *= m; v.y *= m;
        A[nc * LSTR + ns] = v;
    }
    __syncthreads();

    fft96_ip<LSTR, 1, NS, true>(A, tw96, tid);
    fft48_ip<1, LSTR, NC_, true>(A, tw96, tid);

    for (int e = tid; e < NCOL; e += NT_FFT) {
        const int nc = e / NS, ns = e - nc * NS;
        gg[e] = cmuljc(A[nc * LSTR + ns], wp[e]);
    }
}

// ---------------------------------------------------------------------------
// K3: row IFFT 288->96 (crop rows 96..191):
//   out[y] = (1/288) * sum_a conj(e^{-2pi i a/3}) conj(e^{-2pi i a y/288})
//                      * IFFT96_unnorm( G[3s+a] )[y]
// then Ap += conj(csm) * out  (fp32 HW atomics across coils)
// ---------------------------------------------------------------------------
__global__ __launch_bounds__(NT_FFT)
void k_inv_row(const cplx* __restrict__ g, const cplx* __restrict__ csm,
               float* __restrict__ Ap, int cg0, int ncg, int ncga)
{
    __shared__ cplx A[NR * TILE];
    __shared__ cplx tw96[96];
    __shared__ cplx tw288[288];
    const int tid = threadIdx.x;
    build_tw96(tw96, tid);
    build_tw288(tw288, tid);

    const int bid  = blockIdx.x;
    const int tile = bid % TILES;
    const int rem  = bid / TILES;
    const int gc   = rem % ncg;
    const int b    = rem / ncg;
    const int c    = cg0 + gc;
    const int colbase = tile * TILE;

    const cplx* gg = g + (size_t)(b * ncga + gc) * ((size_t)NP * NCOL);

    constexpr int NACC = (NR * TILE) / NT_FFT;   // 9
    cplx acc[NACC];
    #pragma unroll
    for (int i = 0; i < NACC; ++i) acc[i] = make_float2(0.f, 0.f);

    for (int a = 0; a < 3; ++a) {
        __syncthreads();
        for (int e = tid; e < NR * TILE; e += NT_FFT) {
            const int s = e / TILE, t = e - s * TILE;
            A[e] = gg[(size_t)(3 * s + a) * NCOL + colbase + t];
        }
        __syncthreads();
        fft96_ip<TILE, 1, TILE, true>(A, tw96, tid);
        cplx pf = tw96[a * 32];
        pf.y = -pf.y;                       // conj -> e^{+2pi i a/3}
        pf.x *= (1.f / 288.f); pf.y *= (1.f / 288.f);
        #pragma unroll
        for (int i = 0; i < NACC; ++i) {
            const int e = tid + i * NT_FFT;
            const int y = e / TILE;
            cplx w = tw288[a * y]; w.y = -w.y;  // e^{+2pi i a y/288}
            acc[i] = caddc(acc[i], cmulc(cmulc(A[e], w), pf));
        }
    }

    const cplx* cs = csm + ((size_t)b * C_ + c) * NVOX;
    float* apb = Ap + (size_t)b * NVOX * 2;
    #pragma unroll
    for (int i = 0; i < NACC; ++i) {
        const int e = tid + i * NT_FFT;
        const int y = e / TILE, t = e - y * TILE;
        const int gi = y * NCOL + colbase + t;
        const cplx v = cmuljc(acc[i], cs[gi]);
        atomAddF(&apb[2 * gi],     v.x);
        atomAddF(&apb[2 * gi + 1], v.y);
    }
}

// ---------------------------------------------------------------------------
// CG helper kernels
// ---------------------------------------------------------------------------
__device__ inline float block_reduce_sum256(float v){
    #pragma unroll
    for (int o = 32; o >= 1; o >>= 1) v += __shfl_down(v, o, 64);
    __shared__ float sh[4];
    const int lane = threadIdx.x & 63, wv = threadIdx.x >> 6;
    if (lane == 0) sh[wv] = v;
    __syncthreads();
    float s = 0.f;
    if (threadIdx.x == 0) { s = sh[0] + sh[1] + sh[2] + sh[3]; }
    return s;
}

__global__ __launch_bounds__(256)
void k_rr0(const cplx* __restrict__ r, float* __restrict__ sc)
{
    const int i = blockIdx.x * 256 + threadIdx.x;
    const int b = i / NVOX;
    const cplx rv = r[i];
    const float s = block_reduce_sum256(rv.x * rv.x + rv.y * rv.y);
    if (threadIdx.x == 0) atomAddF(&sc[SC_RTR + b], s);
}

__global__ __launch_bounds__(256)
void k_lam_dot(cplx* __restrict__ Ap, const cplx* __restrict__ p,
               const float* __restrict__ lam1, float* __restrict__ sc)
{
    const int i = blockIdx.x * 256 + threadIdx.x;
    const int b = i / NVOX;
    const float lam = lam1[0];
    const cplx pv = p[i];
    cplx ap = Ap[i];
    ap.x += lam * pv.x; ap.y += lam * pv.y;
    Ap[i] = ap;
    const float s = block_reduce_sum256(pv.x * ap.x + pv.y * ap.y);
    if (threadIdx.x == 0) atomAddF(&sc[SC_PAP + b], s);
}

__global__ void k_alpha(float* sc)
{
    const int b = threadIdx.x;
    if (b < B_) {
        const float rtr = sc[SC_RTR + b];
        sc[SC_ACT + b]   = (rtr > 1e-5f) ? 1.f : 0.f;
        sc[SC_ALPHA + b] = rtr / sc[SC_PAP + b];
        sc[SC_RTR1 + b]  = 0.f;
    }
}

__global__ __launch_bounds__(256)
void k_update(cplx* __restrict__ x, cplx* __restrict__ r,
              const cplx* __restrict__ p, const cplx* __restrict__ Ap,
              float* __restrict__ sc)
{
    const int i = blockIdx.x * 256 + threadIdx.x;
    const int b = i / NVOX;
    float loc = 0.f;
    if (sc[SC_ACT + b] != 0.f) {
        const float al = sc[SC_ALPHA + b];
        cplx xv = x[i], rv = r[i];
        const cplx pv = p[i], av = Ap[i];
        xv.x += al * pv.x; xv.y += al * pv.y;
        rv.x -= al * av.x; rv.y -= al * av.y;
        x[i] = xv; r[i] = rv;
        loc = rv.x * rv.x + rv.y * rv.y;
    }
    const float s = block_reduce_sum256(loc);
    if (threadIdx.x == 0) atomAddF(&sc[SC_RTR1 + b], s);
}

__global__ void k_beta(float* sc)
{
    const int b = threadIdx.x;
    if (b < B_) {
        if (sc[SC_ACT + b] != 0.f) {
            sc[SC_BETA + b] = sc[SC_RTR1 + b] / sc[SC_RTR + b];
            sc[SC_RTR + b]  = sc[SC_RTR1 + b];
        } else {
            sc[SC_BETA + b] = 0.f;
        }
        sc[SC_PAP + b] = 0.f;   // pre-zero for next iteration
    }
}

__global__ __launch_bounds__(256)
void k_pupd(cplx* __restrict__ p, const cplx* __restrict__ r,
            const float* __restrict__ sc)
{
    const int i = blockIdx.x * 256 + threadIdx.x;
    const int b = i / NVOX;
    if (sc[SC_ACT + b] != 0.f) {
        const float be = sc[SC_BETA + b];
        const cplx pv = p[i], rv = r[i];
        p[i] = make_float2(rv.x + be * pv.x, rv.y + be * pv.y);
    }
}

// ---------------------------------------------------------------------------
extern "C" void kernel_launch(void* const* d_in, const int* in_sizes, int n_in,
                              void* d_out, int out_size, void* d_ws, size_t ws_size,
                              hipStream_t stream)
{
    const cplx*  rhs  = (const cplx*)d_in[0];
    const cplx*  csm  = (const cplx*)d_in[1];
    const float* mask = (const float*)d_in[2];
    const cplx*  wpsf = (const cplx*)d_in[3];
    const float* lam1 = (const float*)d_in[4];

    const size_t vb = (size_t)B_ * NVOX * sizeof(cplx);   // 7,077,888 B
    char* ws = (char*)d_ws;
    float* sc = (float*)ws;
    cplx* Ap = (cplx*)(ws + 256);
    cplx* r  = (cplx*)(ws + 256 + vb);
    cplx* p  = (cplx*)(ws + 256 + 2 * vb);
    cplx* g  = (cplx*)(ws + 256 + 3 * vb);
    cplx* x  = (cplx*)d_out;

    const size_t fixed   = 256 + 3 * vb;
    const size_t percoil = (size_t)B_ * NP * NCOL * sizeof(cplx);  // 21,233,664 B
    int ncga = 1;
    if (ws_size > fixed) {
        size_t fit = (ws_size - fixed) / percoil;
        ncga = (fit < 1) ? 1 : (fit > (size_t)C_ ? C_ : (int)fit);
    }

    hipMemsetAsync(d_out, 0, vb, stream);       // x0 = 0
    hipMemsetAsync(sc, 0, 256, stream);
    hipMemcpyAsync(r, rhs, vb, hipMemcpyDeviceToDevice, stream);
    hipMemcpyAsync(p, rhs, vb, hipMemcpyDeviceToDevice, stream);
    k_rr0<<<(B_ * NVOX) / 256, 256, 0, stream>>>(r, sc);

    for (int it = 0; it < 10; ++it) {
        hipMemsetAsync(Ap, 0, vb, stream);
        for (int cg0 = 0; cg0 < C_; cg0 += ncga) {
            const int ncg = (C_ - cg0 < ncga) ? (C_ - cg0) : ncga;
            k_fwd_row<<<TILES * ncg * B_, NT_FFT, 0, stream>>>(p, csm, g, cg0, ncg, ncga);
            k_plane  <<<NP    * ncg * B_, NT_FFT, 0, stream>>>(g, wpsf, mask, ncg, ncga);
            k_inv_row<<<TILES * ncg * B_, NT_FFT, 0, stream>>>(g, csm, (float*)Ap, cg0, ncg, ncga);
        }
        k_lam_dot<<<(B_ * NVOX) / 256, 256, 0, stream>>>(Ap, p, lam1, sc);
        k_alpha  <<<1, 64, 0, stream>>>(sc);
        k_update <<<(B_ * NVOX) / 256, 256, 0, stream>>>(x, r, p, Ap, sc);
        k_beta   <<<1, 64, 0, stream>>>(sc);
        k_pupd   <<<(B_ * NVOX) / 256, 256, 0, stream>>>(p, r, sc);
    }
}